// Round 16
// baseline (549.034 us; speedup 1.0000x reference)
//
#include <hip/hip_runtime.h>

// ---------------------------------------------------------------------------
// HedgeHog attention distillation map: pred = (fq.fk^T) rownorm, true = softmax(q0.k0^T/8)
// Output [2,2,16,2048,2048] fp32 = 1.07 GiB -> HBM-write-bound.
//
// v16: wave specialization x LDS-resident B. vmcnt retires IN ORDER, so any
// wave mixing loads+stores stalls its store stream on every load wait (v13/15
// cadence ~1.7us/segment). Producers (w0-3): loads ONLY (deep-prefetched
// A-stream) + MFMA from LDS slab + obuf ring-2. Storers (w4-7): stores ONLY,
// never a vmcnt wait -> free-running store stream. 1 barrier per rg.
// Uniform sweep order (v14 lesson: keep cross-block A-stream L2 synchrony).
// ---------------------------------------------------------------------------

typedef __attribute__((ext_vector_type(8))) short  bf16x8;
typedef __attribute__((ext_vector_type(4))) float  f32x4;

#define NN 2048
#define NBH 32

__device__ float g_part[NBH * 8 * 128];   // fk colsum partials
__device__ float g_normP[NBH * NN];       // 1 / pred row sum
__device__ float g_normT[NBH * NN];       // 1 / true row sum

__device__ __forceinline__ float bf2f(unsigned short u) {
  union { unsigned int i; float f; } v; v.i = ((unsigned int)u) << 16; return v.f;
}
__device__ __forceinline__ unsigned short f2bf(float f) {
  union { float f; unsigned int i; } v; v.f = f;
  unsigned int x = v.i;
  return (unsigned short)((x + 0x7FFFu + ((x >> 16) & 1u)) >> 16);  // RNE
}
__device__ __forceinline__ bf16x8 cvt8(const float* __restrict__ p) {
  bf16x8 v;
#pragma unroll
  for (int i = 0; i < 8; i++) v[i] = (short)f2bf(p[i]);
  return v;
}
__device__ __forceinline__ f32x4 mfma16(bf16x8 a, bf16x8 b, f32x4 c) {
  return __builtin_amdgcn_mfma_f32_16x16x32_bf16(a, b, c, 0, 0, 0);
}

// ---------------------------------------------------------------------------
// Kernel 1: projections + hedgehog features. One wave owns 16 rows.
// ---------------------------------------------------------------------------
__device__ __forceinline__ void proj_chain(
    const bf16x8 ax[2],
    const float* __restrict__ W1, const float* __restrict__ b1,
    const float* __restrict__ W2, const float* __restrict__ b2,
    unsigned short* __restrict__ o1w, unsigned short* __restrict__ o2w,
    unsigned short (*Tq)[72], unsigned short (*Tf)[136],
    long r0, int l15, int g, int l)
{
#pragma unroll
  for (int nt = 0; nt < 4; nt++) {
    f32x4 acc = {0.f, 0.f, 0.f, 0.f};
    acc = mfma16(ax[0], cvt8(W1 + (nt * 16 + l15) * 64 + g * 8), acc);
    acc = mfma16(ax[1], cvt8(W1 + (nt * 16 + l15) * 64 + 32 + g * 8), acc);
    float bv = b1[nt * 16 + l15];
#pragma unroll
    for (int j = 0; j < 4; j++)
      Tq[g * 4 + j][nt * 16 + l15] = f2bf(acc[j] + bv);   // C layout: row=(l>>4)*4+j, col=l&15
  }
#pragma unroll
  for (int i = 0; i < 2; i++) {
    int c = i * 64 + l;
    int r = c >> 3, cc = c & 7;
    *(bf16x8*)(o1w + (r0 + r) * 64 + cc * 8) = *(const bf16x8*)&Tq[r][cc * 8];
  }
  bf16x8 a1[2];
#pragma unroll
  for (int kk = 0; kk < 2; kk++)
    a1[kk] = *(const bf16x8*)&Tq[l15][kk * 32 + g * 8];
#pragma unroll
  for (int nt = 0; nt < 4; nt++) {
    f32x4 acc = {0.f, 0.f, 0.f, 0.f};
    acc = mfma16(a1[0], cvt8(W2 + (nt * 16 + l15) * 64 + g * 8), acc);
    acc = mfma16(a1[1], cvt8(W2 + (nt * 16 + l15) * 64 + 32 + g * 8), acc);
    float bv = b2[nt * 16 + l15];
#pragma unroll
    for (int j = 0; j < 4; j++) {
      float h = acc[j] + bv;
      Tf[g * 4 + j][nt * 16 + l15]      = f2bf(__expf(h));
      Tf[g * 4 + j][64 + nt * 16 + l15] = f2bf(__expf(-h));
    }
  }
#pragma unroll
  for (int i = 0; i < 4; i++) {
    int c = i * 64 + l;
    int r = c >> 4, cc = c & 15;
    *(bf16x8*)(o2w + (r0 + r) * 128 + cc * 8) = *(const bf16x8*)&Tf[r][cc * 8];
  }
}

__global__ __launch_bounds__(256) void k_proj(
    const float* __restrict__ x,
    const float* __restrict__ Wq,  const float* __restrict__ bq,
    const float* __restrict__ Wk,  const float* __restrict__ bk,
    const float* __restrict__ Wmq, const float* __restrict__ bmq,
    const float* __restrict__ Wmk, const float* __restrict__ bmk,
    unsigned short* __restrict__ q0w, unsigned short* __restrict__ k0w,
    unsigned short* __restrict__ fqw, unsigned short* __restrict__ fkw)
{
  const int tid = threadIdx.x;
  const int w = tid >> 6, l = tid & 63;
  const int l15 = l & 15, g = l >> 4;
  const long r0 = ((long)blockIdx.x * 4 + w) * 16;

  __shared__ unsigned short TqS[4][16][72];
  __shared__ unsigned short TfS[4][16][136];

  bf16x8 ax[2];
#pragma unroll
  for (int kk = 0; kk < 2; kk++)
    ax[kk] = cvt8(x + (r0 + l15) * 64 + kk * 32 + g * 8);

  proj_chain(ax, Wq, bq, Wmq, bmq, q0w, fqw, TqS[w], TfS[w], r0, l15, g, l);
  proj_chain(ax, Wk, bk, Wmk, bmk, k0w, fkw, TqS[w], TfS[w], r0, l15, g, l);
}

// ---------------------------------------------------------------------------
// Kernel 2: fk column-sum partials (bh, part): rows part*256..+255.
// ---------------------------------------------------------------------------
__global__ __launch_bounds__(256) void k_colsum1(const unsigned short* __restrict__ fkw)
{
  const int bh = blockIdx.x, part = blockIdx.y;
  const int tid = threadIdx.x;
  const int cg = tid & 15, rg = tid >> 4;
  const unsigned short* fkp = fkw + ((long)bh * NN + part * 256 + rg * 16) * 128 + cg * 8;

  float a8[8] = {0.f, 0.f, 0.f, 0.f, 0.f, 0.f, 0.f, 0.f};
#pragma unroll
  for (int r = 0; r < 16; r++) {
    bf16x8 v = *(const bf16x8*)(fkp + (long)r * 128);
#pragma unroll
    for (int j = 0; j < 8; j++) a8[j] += bf2f((unsigned short)v[j]);
  }
  __shared__ float red[16][132];
#pragma unroll
  for (int j = 0; j < 8; j++) red[rg][cg * 8 + j] = a8[j];
  __syncthreads();
  if (tid < 128) {
    float s = 0.f;
#pragma unroll
    for (int r = 0; r < 16; r++) s += red[r][tid];
    g_part[(bh * 8 + part) * 128 + tid] = s;
  }
}

// ---------------------------------------------------------------------------
// Kernel 3a: pred normalizers (factorized dot with fk colsums).
// ---------------------------------------------------------------------------
__global__ __launch_bounds__(256) void k_normP(const unsigned short* __restrict__ fqw)
{
  const int bh = blockIdx.x, rg = blockIdx.y;   // (32, 16)
  const int tid = threadIdx.x;

  __shared__ float sfk[128];
  if (tid < 128) {
    float s = 0.f;
#pragma unroll
    for (int pt = 0; pt < 8; pt++) s += g_part[bh * 1024 + pt * 128 + tid];
    sfk[tid] = s;
  }
  __syncthreads();
  if (tid < 128) {
    const int row = rg * 128 + tid;
    const unsigned short* p = fqw + ((long)bh * NN + row) * 128;
    float d = 0.f;
#pragma unroll
    for (int i = 0; i < 16; i++) {
      bf16x8 v = *(const bf16x8*)(p + i * 8);
#pragma unroll
      for (int jj = 0; jj < 8; jj++) d += bf2f((unsigned short)v[jj]) * sfk[i * 8 + jj];
    }
    g_normP[bh * NN + row] = 1.0f / d;
  }
}

// ---------------------------------------------------------------------------
// Kernel 3b: true normalizers. Grid (32, 64): 32 rows/block.
// ---------------------------------------------------------------------------
__global__ __launch_bounds__(256) void k_normT(
    const unsigned short* __restrict__ q0w, const unsigned short* __restrict__ k0w)
{
  const int bh = blockIdx.x, rb = blockIdx.y * 32;
  const int tid = threadIdx.x;
  const int w = tid >> 6, l = tid & 63;
  const int l15 = l & 15, g = l >> 4;

  __shared__ float sred[2][4][16];
  const unsigned short* k0p = k0w + (long)bh * NN * 64;

#pragma unroll
  for (int tt = 0; tt < 2; tt++) {
    const unsigned short* qp = q0w + ((long)bh * NN + rb + tt * 16) * 64;
    bf16x8 a0 = *(const bf16x8*)(qp + l15 * 64 + g * 8);
    bf16x8 a1 = *(const bf16x8*)(qp + l15 * 64 + 32 + g * 8);
    float st[4] = {0.f, 0.f, 0.f, 0.f};
    for (int kt = w; kt < 128; kt += 4) {
      const unsigned short* bp = k0p + (long)(kt * 16 + l15) * 64 + g * 8;
      f32x4 acc = {0.f, 0.f, 0.f, 0.f};
      acc = mfma16(a0, *(const bf16x8*)bp, acc);
      acc = mfma16(a1, *(const bf16x8*)(bp + 32), acc);
#pragma unroll
      for (int j = 0; j < 4; j++) st[j] += __expf(acc[j] * 0.125f);
    }
#pragma unroll
    for (int j = 0; j < 4; j++) {
      float v = st[j];
      v += __shfl_xor(v, 1, 16);
      v += __shfl_xor(v, 2, 16);
      v += __shfl_xor(v, 4, 16);
      v += __shfl_xor(v, 8, 16);
      if (l15 == 0) sred[tt][w][g * 4 + j] = v;
    }
  }
  __syncthreads();
  if (tid < 32) {
    const int t2 = tid >> 4, rr = tid & 15;
    float s = sred[t2][0][rr] + sred[t2][1][rr] + sred[t2][2][rr] + sred[t2][3][rr];
    g_normT[bh * NN + rb + t2 * 16 + rr] = 1.0f / s;
  }
}

// ---------------------------------------------------------------------------
// Kernel 4: specialized slab writer. Block = (bh, 128-key slab), 8 waves.
// Producers w0-3 (loads only), storers w4-7 (stores only). Ring-2 obuf,
// 1 raw s_barrier per rg. Uniform sweep order.
// ---------------------------------------------------------------------------
__global__ __launch_bounds__(512, 1) void k_write(
    const unsigned short* __restrict__ q0w, const unsigned short* __restrict__ k0w,
    const unsigned short* __restrict__ fqw, const unsigned short* __restrict__ fkw,
    float* __restrict__ out)
{
  const int bh = blockIdx.x;          // 0..31
  const int slab = blockIdx.y;        // 0..15
  const int tid = threadIdx.x;
  const int w = tid >> 6, l = tid & 63;
  const int l15 = l & 15, g = l >> 4;

  __shared__ unsigned short fkS[128][136];       // 34.8 KB
  __shared__ unsigned short k0S[128][72];        // 18.4 KB
  __shared__ float obuf[2][2][16][132];          // ring-2 x plane x 16x128, 33.8 KB

  const unsigned short* fkp = fkw + ((long)bh * NN + slab * 128) * 128;
  const unsigned short* k0p = k0w + ((long)bh * NN + slab * 128) * 64;
  const unsigned short* fqb = fqw + (long)bh * NN * 128;
  const unsigned short* q0b = q0w + (long)bh * NN * 64;
  const float* npb = g_normP + bh * NN;
  const float* ntb = g_normT + bh * NN;
  const long ob_p = (long)bh * NN * NN + slab * 128;
  const long ob_t = ob_p + (long)NBH * NN * NN;

  // ---- stage slab operands once (all 512 threads) ----
#pragma unroll
  for (int i = 0; i < 4; i++) {
    int c = i * 512 + tid, r = c >> 4, cc = c & 15;
    *(bf16x8*)&fkS[r][cc * 8] = *(const bf16x8*)(fkp + (long)r * 128 + cc * 8);
  }
#pragma unroll
  for (int i = 0; i < 2; i++) {
    int c = i * 512 + tid, r = c >> 3, cc = c & 7;
    *(bf16x8*)&k0S[r][cc * 8] = *(const bf16x8*)(k0p + (long)r * 64 + cc * 8);
  }
  __syncthreads();

  if (w < 4) {
    // ========================= producers =========================
    bf16x8 aq[2][4], ak[2][2];
    f32x4 aip[2], ait[2];

#define PF(RG1, S) {                                                           \
      if ((RG1) < 128) {                                                       \
        const int qr_ = (RG1) * 16;                                            \
        _Pragma("unroll")                                                      \
        for (int kk = 0; kk < 4; kk++)                                         \
          aq[S][kk] = *(const bf16x8*)(fqb + (long)(qr_ + l15) * 128 + kk * 32 + g * 8); \
        _Pragma("unroll")                                                      \
        for (int kk = 0; kk < 2; kk++)                                         \
          ak[S][kk] = *(const bf16x8*)(q0b + (long)(qr_ + l15) * 64 + kk * 32 + g * 8);  \
        aip[S] = *(const f32x4*)(npb + qr_ + g * 4);                           \
        ait[S] = *(const f32x4*)(ntb + qr_ + g * 4);                           \
      }                                                                        \
    }

#define COMP(S) {                                                              \
      _Pragma("unroll")                                                        \
      for (int t = 0; t < 2; t++) {                                            \
        const int key = w * 32 + t * 16 + l15;                                 \
        f32x4 accp = {0.f, 0.f, 0.f, 0.f};                                     \
        _Pragma("unroll")                                                      \
        for (int kk = 0; kk < 4; kk++)                                         \
          accp = mfma16(aq[S][kk], *(const bf16x8*)&fkS[key][kk * 32 + g * 8], accp); \
        f32x4 acct = {0.f, 0.f, 0.f, 0.f};                                     \
        acct = mfma16(ak[S][0], *(const bf16x8*)&k0S[key][g * 8], acct);       \
        acct = mfma16(ak[S][1], *(const bf16x8*)&k0S[key][32 + g * 8], acct);  \
        _Pragma("unroll")                                                      \
        for (int j = 0; j < 4; j++) {                                          \
          obuf[S][0][g * 4 + j][key] = accp[j] * aip[S][j];                    \
          obuf[S][1][g * 4 + j][key] = __expf(acct[j] * 0.125f) * ait[S][j];   \
        }                                                                      \
      }                                                                        \
    }

    PF(0, 0);
    PF(1, 1);
#pragma unroll 1
    for (int rg2 = 0; rg2 < 64; rg2++) {
      // rg even (set 0)
      COMP(0);
      PF(2 * rg2 + 2, 0);
      asm volatile("s_waitcnt lgkmcnt(0)" ::: "memory");
      __builtin_amdgcn_s_barrier();
      __builtin_amdgcn_sched_barrier(0);
      // rg odd (set 1)
      COMP(1);
      PF(2 * rg2 + 3, 1);
      asm volatile("s_waitcnt lgkmcnt(0)" ::: "memory");
      __builtin_amdgcn_s_barrier();
      __builtin_amdgcn_sched_barrier(0);
    }
#undef PF
#undef COMP
  } else {
    // ========================= storers =========================
    const int sw = w - 4;
    const int col = (l & 31) * 4;
    const int rsel = (l >> 5);

#define STORE(RG) {                                                            \
      const int ring_ = (RG) & 1;                                              \
      const long rb_ = (long)((RG) * 16);                                      \
      _Pragma("unroll")                                                        \
      for (int pl = 0; pl < 2; pl++) {                                         \
        const long ob = (pl ? ob_t : ob_p);                                    \
        _Pragma("unroll")                                                      \
        for (int i = 0; i < 2; i++) {                                          \
          const int row = sw * 4 + 2 * i + rsel;                               \
          f32x4 v = *(const f32x4*)&obuf[ring_][pl][row][col];                 \
          *(f32x4*)(out + ob + (rb_ + row) * NN + col) = v;                    \
        }                                                                      \
      }                                                                        \
    }

    __builtin_amdgcn_s_barrier();               // rg 0 produced
    __builtin_amdgcn_sched_barrier(0);
#pragma unroll 1
    for (int rg = 1; rg < 128; rg++) {
      STORE(rg - 1);
      __builtin_amdgcn_s_barrier();             // rg produced; rg-1 consumed
      __builtin_amdgcn_sched_barrier(0);
    }
    STORE(127);                                 // drain
#undef STORE
  }
}

extern "C" void kernel_launch(void* const* d_in, const int* in_sizes, int n_in,
                              void* d_out, int out_size, void* d_ws, size_t ws_size,
                              hipStream_t stream) {
  const float* x   = (const float*)d_in[0];
  const float* Wq  = (const float*)d_in[1];
  const float* bq  = (const float*)d_in[2];
  const float* Wk  = (const float*)d_in[3];
  const float* bk  = (const float*)d_in[4];
  const float* Wmq = (const float*)d_in[5];
  const float* bmq = (const float*)d_in[6];
  const float* Wmk = (const float*)d_in[7];
  const float* bmk = (const float*)d_in[8];
  float* out = (float*)d_out;

  // ws layout (bf16): q0[32][2048][64], k0[...], fq[32][2048][128], fk[...] = 48 MB
  unsigned short* q0w = (unsigned short*)d_ws;
  unsigned short* k0w = q0w + (long)NBH * NN * 64;
  unsigned short* fqw = k0w + (long)NBH * NN * 64;
  unsigned short* fkw = fqw + (long)NBH * NN * 128;

  hipLaunchKernelGGL(k_proj, dim3(1024), dim3(256), 0, stream,
                     x, Wq, bq, Wk, bk, Wmq, bmq, Wmk, bmk, q0w, k0w, fqw, fkw);
  hipLaunchKernelGGL(k_colsum1, dim3(NBH, 8), dim3(256), 0, stream, fkw);
  hipLaunchKernelGGL(k_normP, dim3(NBH, 16), dim3(256), 0, stream, fqw);
  hipLaunchKernelGGL(k_normT, dim3(NBH, 64), dim3(256), 0, stream, q0w, k0w);
  hipLaunchKernelGGL(k_write, dim3(NBH, 16), dim3(512), 0, stream,
                     q0w, k0w, fqw, fkw, out);
}

// Round 17
// 532.583 us; speedup vs baseline: 1.0309x; 1.0309x over previous
//
#include <hip/hip_runtime.h>

// ---------------------------------------------------------------------------
// HedgeHog attention distillation map: pred = (fq.fk^T) rownorm, true = softmax(q0.k0^T/8)
// Output [2,2,16,2048,2048] fp32 = 1.07 GiB -> HBM-write-bound.
//
// v17 = v13 (best, 487us) + ONE change: A-stream prefetch cover 1 -> 3
// rg-periods (4 register sets, unroll-by-4 sweep). v13's cadence was ~8000cy
// per rg vs ~600cy static work: the A-loads' thrashed-L2 latency with only
// depth-1 cover. Deeper cover also ages stores 3 periods before any vmcnt
// wait can touch them (in-order FIFO). All else identical to v13/v15.
// ---------------------------------------------------------------------------

typedef __attribute__((ext_vector_type(8))) short  bf16x8;
typedef __attribute__((ext_vector_type(4))) float  f32x4;

#define NN 2048
#define NBH 32

__device__ float g_part[NBH * 8 * 128];   // fk colsum partials
__device__ float g_normP[NBH * NN];       // 1 / pred row sum
__device__ float g_normT[NBH * NN];       // 1 / true row sum

__device__ __forceinline__ float bf2f(unsigned short u) {
  union { unsigned int i; float f; } v; v.i = ((unsigned int)u) << 16; return v.f;
}
__device__ __forceinline__ unsigned short f2bf(float f) {
  union { float f; unsigned int i; } v; v.f = f;
  unsigned int x = v.i;
  return (unsigned short)((x + 0x7FFFu + ((x >> 16) & 1u)) >> 16);  // RNE
}
__device__ __forceinline__ bf16x8 cvt8(const float* __restrict__ p) {
  bf16x8 v;
#pragma unroll
  for (int i = 0; i < 8; i++) v[i] = (short)f2bf(p[i]);
  return v;
}
__device__ __forceinline__ f32x4 mfma16(bf16x8 a, bf16x8 b, f32x4 c) {
  return __builtin_amdgcn_mfma_f32_16x16x32_bf16(a, b, c, 0, 0, 0);
}

// ---------------------------------------------------------------------------
// Kernel 1: projections + hedgehog features. One wave owns 16 rows.
// ---------------------------------------------------------------------------
__device__ __forceinline__ void proj_chain(
    const bf16x8 ax[2],
    const float* __restrict__ W1, const float* __restrict__ b1,
    const float* __restrict__ W2, const float* __restrict__ b2,
    unsigned short* __restrict__ o1w, unsigned short* __restrict__ o2w,
    unsigned short (*Tq)[72], unsigned short (*Tf)[136],
    long r0, int l15, int g, int l)
{
#pragma unroll
  for (int nt = 0; nt < 4; nt++) {
    f32x4 acc = {0.f, 0.f, 0.f, 0.f};
    acc = mfma16(ax[0], cvt8(W1 + (nt * 16 + l15) * 64 + g * 8), acc);
    acc = mfma16(ax[1], cvt8(W1 + (nt * 16 + l15) * 64 + 32 + g * 8), acc);
    float bv = b1[nt * 16 + l15];
#pragma unroll
    for (int j = 0; j < 4; j++)
      Tq[g * 4 + j][nt * 16 + l15] = f2bf(acc[j] + bv);   // C layout: row=(l>>4)*4+j, col=l&15
  }
#pragma unroll
  for (int i = 0; i < 2; i++) {
    int c = i * 64 + l;
    int r = c >> 3, cc = c & 7;
    *(bf16x8*)(o1w + (r0 + r) * 64 + cc * 8) = *(const bf16x8*)&Tq[r][cc * 8];
  }
  bf16x8 a1[2];
#pragma unroll
  for (int kk = 0; kk < 2; kk++)
    a1[kk] = *(const bf16x8*)&Tq[l15][kk * 32 + g * 8];
#pragma unroll
  for (int nt = 0; nt < 4; nt++) {
    f32x4 acc = {0.f, 0.f, 0.f, 0.f};
    acc = mfma16(a1[0], cvt8(W2 + (nt * 16 + l15) * 64 + g * 8), acc);
    acc = mfma16(a1[1], cvt8(W2 + (nt * 16 + l15) * 64 + 32 + g * 8), acc);
    float bv = b2[nt * 16 + l15];
#pragma unroll
    for (int j = 0; j < 4; j++) {
      float h = acc[j] + bv;
      Tf[g * 4 + j][nt * 16 + l15]      = f2bf(__expf(h));
      Tf[g * 4 + j][64 + nt * 16 + l15] = f2bf(__expf(-h));
    }
  }
#pragma unroll
  for (int i = 0; i < 4; i++) {
    int c = i * 64 + l;
    int r = c >> 4, cc = c & 15;
    *(bf16x8*)(o2w + (r0 + r) * 128 + cc * 8) = *(const bf16x8*)&Tf[r][cc * 8];
  }
}

__global__ __launch_bounds__(256) void k_proj(
    const float* __restrict__ x,
    const float* __restrict__ Wq,  const float* __restrict__ bq,
    const float* __restrict__ Wk,  const float* __restrict__ bk,
    const float* __restrict__ Wmq, const float* __restrict__ bmq,
    const float* __restrict__ Wmk, const float* __restrict__ bmk,
    unsigned short* __restrict__ q0w, unsigned short* __restrict__ k0w,
    unsigned short* __restrict__ fqw, unsigned short* __restrict__ fkw)
{
  const int tid = threadIdx.x;
  const int w = tid >> 6, l = tid & 63;
  const int l15 = l & 15, g = l >> 4;
  const long r0 = ((long)blockIdx.x * 4 + w) * 16;

  __shared__ unsigned short TqS[4][16][72];
  __shared__ unsigned short TfS[4][16][136];

  bf16x8 ax[2];
#pragma unroll
  for (int kk = 0; kk < 2; kk++)
    ax[kk] = cvt8(x + (r0 + l15) * 64 + kk * 32 + g * 8);

  proj_chain(ax, Wq, bq, Wmq, bmq, q0w, fqw, TqS[w], TfS[w], r0, l15, g, l);
  proj_chain(ax, Wk, bk, Wmk, bmk, k0w, fkw, TqS[w], TfS[w], r0, l15, g, l);
}

// ---------------------------------------------------------------------------
// Kernel 2: fk column-sum partials (bh, part): rows part*256..+255.
// ---------------------------------------------------------------------------
__global__ __launch_bounds__(256) void k_colsum1(const unsigned short* __restrict__ fkw)
{
  const int bh = blockIdx.x, part = blockIdx.y;
  const int tid = threadIdx.x;
  const int cg = tid & 15, rg = tid >> 4;
  const unsigned short* fkp = fkw + ((long)bh * NN + part * 256 + rg * 16) * 128 + cg * 8;

  float a8[8] = {0.f, 0.f, 0.f, 0.f, 0.f, 0.f, 0.f, 0.f};
#pragma unroll
  for (int r = 0; r < 16; r++) {
    bf16x8 v = *(const bf16x8*)(fkp + (long)r * 128);
#pragma unroll
    for (int j = 0; j < 8; j++) a8[j] += bf2f((unsigned short)v[j]);
  }
  __shared__ float red[16][132];
#pragma unroll
  for (int j = 0; j < 8; j++) red[rg][cg * 8 + j] = a8[j];
  __syncthreads();
  if (tid < 128) {
    float s = 0.f;
#pragma unroll
    for (int r = 0; r < 16; r++) s += red[r][tid];
    g_part[(bh * 8 + part) * 128 + tid] = s;
  }
}

// ---------------------------------------------------------------------------
// Kernel 3a: pred normalizers (factorized dot with fk colsums).
// ---------------------------------------------------------------------------
__global__ __launch_bounds__(256) void k_normP(const unsigned short* __restrict__ fqw)
{
  const int bh = blockIdx.x, rg = blockIdx.y;   // (32, 16)
  const int tid = threadIdx.x;

  __shared__ float sfk[128];
  if (tid < 128) {
    float s = 0.f;
#pragma unroll
    for (int pt = 0; pt < 8; pt++) s += g_part[bh * 1024 + pt * 128 + tid];
    sfk[tid] = s;
  }
  __syncthreads();
  if (tid < 128) {
    const int row = rg * 128 + tid;
    const unsigned short* p = fqw + ((long)bh * NN + row) * 128;
    float d = 0.f;
#pragma unroll
    for (int i = 0; i < 16; i++) {
      bf16x8 v = *(const bf16x8*)(p + i * 8);
#pragma unroll
      for (int jj = 0; jj < 8; jj++) d += bf2f((unsigned short)v[jj]) * sfk[i * 8 + jj];
    }
    g_normP[bh * NN + row] = 1.0f / d;
  }
}

// ---------------------------------------------------------------------------
// Kernel 3b: true normalizers. Grid (32, 64): 32 rows/block.
// ---------------------------------------------------------------------------
__global__ __launch_bounds__(256) void k_normT(
    const unsigned short* __restrict__ q0w, const unsigned short* __restrict__ k0w)
{
  const int bh = blockIdx.x, rb = blockIdx.y * 32;
  const int tid = threadIdx.x;
  const int w = tid >> 6, l = tid & 63;
  const int l15 = l & 15, g = l >> 4;

  __shared__ float sred[2][4][16];
  const unsigned short* k0p = k0w + (long)bh * NN * 64;

#pragma unroll
  for (int tt = 0; tt < 2; tt++) {
    const unsigned short* qp = q0w + ((long)bh * NN + rb + tt * 16) * 64;
    bf16x8 a0 = *(const bf16x8*)(qp + l15 * 64 + g * 8);
    bf16x8 a1 = *(const bf16x8*)(qp + l15 * 64 + 32 + g * 8);
    float st[4] = {0.f, 0.f, 0.f, 0.f};
    for (int kt = w; kt < 128; kt += 4) {
      const unsigned short* bp = k0p + (long)(kt * 16 + l15) * 64 + g * 8;
      f32x4 acc = {0.f, 0.f, 0.f, 0.f};
      acc = mfma16(a0, *(const bf16x8*)bp, acc);
      acc = mfma16(a1, *(const bf16x8*)(bp + 32), acc);
#pragma unroll
      for (int j = 0; j < 4; j++) st[j] += __expf(acc[j] * 0.125f);
    }
#pragma unroll
    for (int j = 0; j < 4; j++) {
      float v = st[j];
      v += __shfl_xor(v, 1, 16);
      v += __shfl_xor(v, 2, 16);
      v += __shfl_xor(v, 4, 16);
      v += __shfl_xor(v, 8, 16);
      if (l15 == 0) sred[tt][w][g * 4 + j] = v;
    }
  }
  __syncthreads();
  if (tid < 32) {
    const int t2 = tid >> 4, rr = tid & 15;
    float s = sred[t2][0][rr] + sred[t2][1][rr] + sred[t2][2][rr] + sred[t2][3][rr];
    g_normT[bh * NN + rb + t2 * 16 + rr] = 1.0f / s;
  }
}

// ---------------------------------------------------------------------------
// Kernel 4: slab writer (v13 structure) + depth-3 A-prefetch (4 reg sets).
// Block = (bh, 128-key slab), 4 waves, 2 blocks/CU. fk/k0 slab LDS-resident;
// UNIFORM sweep of 128 row-groups, unrolled by 4.
// ---------------------------------------------------------------------------
__global__ __launch_bounds__(256, 2) void k_write(
    const unsigned short* __restrict__ q0w, const unsigned short* __restrict__ k0w,
    const unsigned short* __restrict__ fqw, const unsigned short* __restrict__ fkw,
    float* __restrict__ out)
{
  const int bh = blockIdx.x;          // 0..31
  const int slab = blockIdx.y;        // 0..15 (128-key slab)
  const int tid = threadIdx.x;
  const int w = tid >> 6, l = tid & 63;
  const int l15 = l & 15, g = l >> 4;

  __shared__ unsigned short fkS[128][136];  // slab operands (padded rows)
  __shared__ unsigned short k0S[128][72];
  __shared__ float obuf[2][16][132];        // [0]=pred strip, [1]=true strip

  const unsigned short* fkp = fkw + ((long)bh * NN + slab * 128) * 128;
  const unsigned short* k0p = k0w + ((long)bh * NN + slab * 128) * 64;
  const unsigned short* fqb = fqw + (long)bh * NN * 128;
  const unsigned short* q0b = q0w + (long)bh * NN * 64;
  const float* npb = g_normP + bh * NN;
  const float* ntb = g_normT + bh * NN;
  const long ob_p = (long)bh * NN * NN + slab * 128;
  const long ob_t = ob_p + (long)NBH * NN * NN;

  // ---- stage slab operands once ----
#pragma unroll
  for (int i = 0; i < 8; i++) {
    int c = i * 256 + tid, r = c >> 4, cc = c & 15;
    *(bf16x8*)&fkS[r][cc * 8] = *(const bf16x8*)(fkp + (long)r * 128 + cc * 8);
  }
#pragma unroll
  for (int i = 0; i < 4; i++) {
    int c = i * 256 + tid, r = c >> 3, cc = c & 7;
    *(bf16x8*)&k0S[r][cc * 8] = *(const bf16x8*)(k0p + (long)r * 64 + cc * 8);
  }
  __syncthreads();

  // ---- 4 A-frag register sets (depth-3 prefetch cover) ----
  bf16x8 aqA[4], aqB[4], aqC[4], aqD[4];
  bf16x8 akA[2], akB[2], akC[2], akD[2];
  f32x4 ipA, ipB, ipC, ipD, itA, itB, itC, itD;

#define PF(RG1, AQ, AK, IP, IT) {                                              \
    if ((RG1) < 128) {                                                         \
      const int qr_ = (RG1) * 16;                                              \
      _Pragma("unroll")                                                        \
      for (int kk = 0; kk < 4; kk++)                                           \
        AQ[kk] = *(const bf16x8*)(fqb + (long)(qr_ + l15) * 128 + kk * 32 + g * 8); \
      _Pragma("unroll")                                                        \
      for (int kk = 0; kk < 2; kk++)                                           \
        AK[kk] = *(const bf16x8*)(q0b + (long)(qr_ + l15) * 64 + kk * 32 + g * 8);  \
      IP = *(const f32x4*)(npb + qr_ + g * 4);                                 \
      IT = *(const f32x4*)(ntb + qr_ + g * 4);                                 \
    }                                                                          \
  }

#define CPRED(AQ, IP) {                                                        \
    _Pragma("unroll")                                                          \
    for (int t = 0; t < 2; t++) {                                              \
      const int key = w * 32 + t * 16 + l15;                                   \
      f32x4 acc = {0.f, 0.f, 0.f, 0.f};                                        \
      _Pragma("unroll")                                                        \
      for (int kk = 0; kk < 4; kk++)                                           \
        acc = mfma16(AQ[kk], *(const bf16x8*)&fkS[key][kk * 32 + g * 8], acc); \
      _Pragma("unroll")                                                        \
      for (int j = 0; j < 4; j++)                                              \
        obuf[0][g * 4 + j][key] = acc[j] * IP[j];                              \
    }                                                                          \
  }

#define CTRUE(AK, IT) {                                                        \
    _Pragma("unroll")                                                          \
    for (int t = 0; t < 2; t++) {                                              \
      const int key = w * 32 + t * 16 + l15;                                   \
      f32x4 acc = {0.f, 0.f, 0.f, 0.f};                                        \
      acc = mfma16(AK[0], *(const bf16x8*)&k0S[key][g * 8], acc);              \
      acc = mfma16(AK[1], *(const bf16x8*)&k0S[key][32 + g * 8], acc);         \
      _Pragma("unroll")                                                        \
      for (int j = 0; j < 4; j++)                                              \
        obuf[1][g * 4 + j][key] = __expf(acc[j] * 0.125f) * IT[j];             \
    }                                                                          \
  }

#define STOREV(PL, RG2) {                                                      \
    const long ob = ((PL) ? ob_t : ob_p) + (long)((RG2) * 16) * NN;            \
    const int row0 = w * 4 + (l >> 5), col = (l & 31) * 4;                     \
    f32x4 v0_ = *(const f32x4*)&obuf[PL][row0][col];                           \
    f32x4 v1_ = *(const f32x4*)&obuf[PL][row0 + 2][col];                       \
    *(f32x4*)(out + ob + (long)row0 * NN + col)       = v0_;                   \
    *(f32x4*)(out + ob + (long)(row0 + 2) * NN + col) = v1_;                   \
  }

#define BODY(RG, AQ, AK, IP, IT, PAQ, PAK, PIP, PIT) {                         \
    /* --- pred segment --- */                                                 \
    PF((RG) + 3, PAQ, PAK, PIP, PIT);                                          \
    if ((RG) > 0) STOREV(1, (RG) - 1);                                         \
    CPRED(AQ, IP);                                                             \
    asm volatile("s_waitcnt lgkmcnt(0)" ::: "memory");                         \
    __builtin_amdgcn_s_barrier();                                              \
    __builtin_amdgcn_sched_barrier(0);                                         \
    /* --- true segment --- */                                                 \
    STOREV(0, RG);                                                             \
    CTRUE(AK, IT);                                                             \
    asm volatile("s_waitcnt lgkmcnt(0)" ::: "memory");                         \
    __builtin_amdgcn_s_barrier();                                              \
    __builtin_amdgcn_sched_barrier(0);                                         \
  }

  PF(0, aqA, akA, ipA, itA);
  PF(1, aqB, akB, ipB, itB);
  PF(2, aqC, akC, ipC, itC);

#pragma unroll 1
  for (int rg4 = 0; rg4 < 32; rg4++) {
    const int rg = rg4 * 4;
    BODY(rg + 0, aqA, akA, ipA, itA, aqD, akD, ipD, itD);
    BODY(rg + 1, aqB, akB, ipB, itB, aqA, akA, ipA, itA);
    BODY(rg + 2, aqC, akC, ipC, itC, aqB, akB, ipB, itB);
    BODY(rg + 3, aqD, akD, ipD, itD, aqC, akC, ipC, itC);
  }
  STOREV(1, 127);                     // drain: last true strip

#undef PF
#undef CPRED
#undef CTRUE
#undef STOREV
#undef BODY
}

extern "C" void kernel_launch(void* const* d_in, const int* in_sizes, int n_in,
                              void* d_out, int out_size, void* d_ws, size_t ws_size,
                              hipStream_t stream) {
  const float* x   = (const float*)d_in[0];
  const float* Wq  = (const float*)d_in[1];
  const float* bq  = (const float*)d_in[2];
  const float* Wk  = (const float*)d_in[3];
  const float* bk  = (const float*)d_in[4];
  const float* Wmq = (const float*)d_in[5];
  const float* bmq = (const float*)d_in[6];
  const float* Wmk = (const float*)d_in[7];
  const float* bmk = (const float*)d_in[8];
  float* out = (float*)d_out;

  // ws layout (bf16): q0[32][2048][64], k0[...], fq[32][2048][128], fk[...] = 48 MB
  unsigned short* q0w = (unsigned short*)d_ws;
  unsigned short* k0w = q0w + (long)NBH * NN * 64;
  unsigned short* fqw = k0w + (long)NBH * NN * 64;
  unsigned short* fkw = fqw + (long)NBH * NN * 128;

  hipLaunchKernelGGL(k_proj, dim3(1024), dim3(256), 0, stream,
                     x, Wq, bq, Wk, bk, Wmq, bmq, Wmk, bmk, q0w, k0w, fqw, fkw);
  hipLaunchKernelGGL(k_colsum1, dim3(NBH, 8), dim3(256), 0, stream, fkw);
  hipLaunchKernelGGL(k_normP, dim3(NBH, 16), dim3(256), 0, stream, fqw);
  hipLaunchKernelGGL(k_normT, dim3(NBH, 64), dim3(256), 0, stream, q0w, k0w);
  hipLaunchKernelGGL(k_write, dim3(NBH, 16), dim3(256), 0, stream,
                     q0w, k0w, fqw, fkw, out);
}

// Round 18
// 452.475 us; speedup vs baseline: 1.2134x; 1.1770x over previous
//
#include <hip/hip_runtime.h>

// ---------------------------------------------------------------------------
// HedgeHog attention distillation map: pred = (fq.fk^T) rownorm, true = softmax(q0.k0^T/8)
// Output [2,2,16,2048,2048] fp32 = 1.07 GiB -> HBM-write-bound.
//
// v18: LDS-resident slab (v13's win) x WAVE-PRIVATE barrier-free sweep.
// v13's cadence (~1.7us/segment) survived falsification of WAR-rotation,
// prefetch-depth, specialization, norms -> remaining suspect is the barrier
// convoy (block-wide lockstep => only ~8KB stores in flight per block =>
// 512 x 8KB / 1.7us = 2.4 TB/s = the wall). Now: each of 8 waves owns its
// own rg sequence + private LDS transpose buffer + store stream; only
// wave-local lgkmcnt waits; ZERO barriers in the sweep. Uniform rg order
// across blocks (v14 lesson).
// ---------------------------------------------------------------------------

typedef __attribute__((ext_vector_type(8))) short  bf16x8;
typedef __attribute__((ext_vector_type(4))) float  f32x4;

#define NN 2048
#define NBH 32

__device__ float g_part[NBH * 8 * 128];   // fk colsum partials
__device__ float g_normP[NBH * NN];       // 1 / pred row sum
__device__ float g_normT[NBH * NN];       // 1 / true row sum

__device__ __forceinline__ float bf2f(unsigned short u) {
  union { unsigned int i; float f; } v; v.i = ((unsigned int)u) << 16; return v.f;
}
__device__ __forceinline__ unsigned short f2bf(float f) {
  union { float f; unsigned int i; } v; v.f = f;
  unsigned int x = v.i;
  return (unsigned short)((x + 0x7FFFu + ((x >> 16) & 1u)) >> 16);  // RNE
}
__device__ __forceinline__ bf16x8 cvt8(const float* __restrict__ p) {
  bf16x8 v;
#pragma unroll
  for (int i = 0; i < 8; i++) v[i] = (short)f2bf(p[i]);
  return v;
}
__device__ __forceinline__ f32x4 mfma16(bf16x8 a, bf16x8 b, f32x4 c) {
  return __builtin_amdgcn_mfma_f32_16x16x32_bf16(a, b, c, 0, 0, 0);
}

// ---------------------------------------------------------------------------
// Kernel 1: projections + hedgehog features. One wave owns 16 rows.
// ---------------------------------------------------------------------------
__device__ __forceinline__ void proj_chain(
    const bf16x8 ax[2],
    const float* __restrict__ W1, const float* __restrict__ b1,
    const float* __restrict__ W2, const float* __restrict__ b2,
    unsigned short* __restrict__ o1w, unsigned short* __restrict__ o2w,
    unsigned short (*Tq)[72], unsigned short (*Tf)[136],
    long r0, int l15, int g, int l)
{
#pragma unroll
  for (int nt = 0; nt < 4; nt++) {
    f32x4 acc = {0.f, 0.f, 0.f, 0.f};
    acc = mfma16(ax[0], cvt8(W1 + (nt * 16 + l15) * 64 + g * 8), acc);
    acc = mfma16(ax[1], cvt8(W1 + (nt * 16 + l15) * 64 + 32 + g * 8), acc);
    float bv = b1[nt * 16 + l15];
#pragma unroll
    for (int j = 0; j < 4; j++)
      Tq[g * 4 + j][nt * 16 + l15] = f2bf(acc[j] + bv);   // C layout: row=(l>>4)*4+j, col=l&15
  }
#pragma unroll
  for (int i = 0; i < 2; i++) {
    int c = i * 64 + l;
    int r = c >> 3, cc = c & 7;
    *(bf16x8*)(o1w + (r0 + r) * 64 + cc * 8) = *(const bf16x8*)&Tq[r][cc * 8];
  }
  bf16x8 a1[2];
#pragma unroll
  for (int kk = 0; kk < 2; kk++)
    a1[kk] = *(const bf16x8*)&Tq[l15][kk * 32 + g * 8];
#pragma unroll
  for (int nt = 0; nt < 4; nt++) {
    f32x4 acc = {0.f, 0.f, 0.f, 0.f};
    acc = mfma16(a1[0], cvt8(W2 + (nt * 16 + l15) * 64 + g * 8), acc);
    acc = mfma16(a1[1], cvt8(W2 + (nt * 16 + l15) * 64 + 32 + g * 8), acc);
    float bv = b2[nt * 16 + l15];
#pragma unroll
    for (int j = 0; j < 4; j++) {
      float h = acc[j] + bv;
      Tf[g * 4 + j][nt * 16 + l15]      = f2bf(__expf(h));
      Tf[g * 4 + j][64 + nt * 16 + l15] = f2bf(__expf(-h));
    }
  }
#pragma unroll
  for (int i = 0; i < 4; i++) {
    int c = i * 64 + l;
    int r = c >> 4, cc = c & 15;
    *(bf16x8*)(o2w + (r0 + r) * 128 + cc * 8) = *(const bf16x8*)&Tf[r][cc * 8];
  }
}

__global__ __launch_bounds__(256) void k_proj(
    const float* __restrict__ x,
    const float* __restrict__ Wq,  const float* __restrict__ bq,
    const float* __restrict__ Wk,  const float* __restrict__ bk,
    const float* __restrict__ Wmq, const float* __restrict__ bmq,
    const float* __restrict__ Wmk, const float* __restrict__ bmk,
    unsigned short* __restrict__ q0w, unsigned short* __restrict__ k0w,
    unsigned short* __restrict__ fqw, unsigned short* __restrict__ fkw)
{
  const int tid = threadIdx.x;
  const int w = tid >> 6, l = tid & 63;
  const int l15 = l & 15, g = l >> 4;
  const long r0 = ((long)blockIdx.x * 4 + w) * 16;

  __shared__ unsigned short TqS[4][16][72];
  __shared__ unsigned short TfS[4][16][136];

  bf16x8 ax[2];
#pragma unroll
  for (int kk = 0; kk < 2; kk++)
    ax[kk] = cvt8(x + (r0 + l15) * 64 + kk * 32 + g * 8);

  proj_chain(ax, Wq, bq, Wmq, bmq, q0w, fqw, TqS[w], TfS[w], r0, l15, g, l);
  proj_chain(ax, Wk, bk, Wmk, bmk, k0w, fkw, TqS[w], TfS[w], r0, l15, g, l);
}

// ---------------------------------------------------------------------------
// Kernel 2: fk column-sum partials (bh, part): rows part*256..+255.
// ---------------------------------------------------------------------------
__global__ __launch_bounds__(256) void k_colsum1(const unsigned short* __restrict__ fkw)
{
  const int bh = blockIdx.x, part = blockIdx.y;
  const int tid = threadIdx.x;
  const int cg = tid & 15, rg = tid >> 4;
  const unsigned short* fkp = fkw + ((long)bh * NN + part * 256 + rg * 16) * 128 + cg * 8;

  float a8[8] = {0.f, 0.f, 0.f, 0.f, 0.f, 0.f, 0.f, 0.f};
#pragma unroll
  for (int r = 0; r < 16; r++) {
    bf16x8 v = *(const bf16x8*)(fkp + (long)r * 128);
#pragma unroll
    for (int j = 0; j < 8; j++) a8[j] += bf2f((unsigned short)v[j]);
  }
  __shared__ float red[16][132];
#pragma unroll
  for (int j = 0; j < 8; j++) red[rg][cg * 8 + j] = a8[j];
  __syncthreads();
  if (tid < 128) {
    float s = 0.f;
#pragma unroll
    for (int r = 0; r < 16; r++) s += red[r][tid];
    g_part[(bh * 8 + part) * 128 + tid] = s;
  }
}

// ---------------------------------------------------------------------------
// Kernel 3a: pred normalizers (factorized dot with fk colsums).
// ---------------------------------------------------------------------------
__global__ __launch_bounds__(256) void k_normP(const unsigned short* __restrict__ fqw)
{
  const int bh = blockIdx.x, rg = blockIdx.y;   // (32, 16)
  const int tid = threadIdx.x;

  __shared__ float sfk[128];
  if (tid < 128) {
    float s = 0.f;
#pragma unroll
    for (int pt = 0; pt < 8; pt++) s += g_part[bh * 1024 + pt * 128 + tid];
    sfk[tid] = s;
  }
  __syncthreads();
  if (tid < 128) {
    const int row = rg * 128 + tid;
    const unsigned short* p = fqw + ((long)bh * NN + row) * 128;
    float d = 0.f;
#pragma unroll
    for (int i = 0; i < 16; i++) {
      bf16x8 v = *(const bf16x8*)(p + i * 8);
#pragma unroll
      for (int jj = 0; jj < 8; jj++) d += bf2f((unsigned short)v[jj]) * sfk[i * 8 + jj];
    }
    g_normP[bh * NN + row] = 1.0f / d;
  }
}

// ---------------------------------------------------------------------------
// Kernel 3b: true normalizers. Grid (32, 64): 32 rows/block.
// ---------------------------------------------------------------------------
__global__ __launch_bounds__(256) void k_normT(
    const unsigned short* __restrict__ q0w, const unsigned short* __restrict__ k0w)
{
  const int bh = blockIdx.x, rb = blockIdx.y * 32;
  const int tid = threadIdx.x;
  const int w = tid >> 6, l = tid & 63;
  const int l15 = l & 15, g = l >> 4;

  __shared__ float sred[2][4][16];
  const unsigned short* k0p = k0w + (long)bh * NN * 64;

#pragma unroll
  for (int tt = 0; tt < 2; tt++) {
    const unsigned short* qp = q0w + ((long)bh * NN + rb + tt * 16) * 64;
    bf16x8 a0 = *(const bf16x8*)(qp + l15 * 64 + g * 8);
    bf16x8 a1 = *(const bf16x8*)(qp + l15 * 64 + 32 + g * 8);
    float st[4] = {0.f, 0.f, 0.f, 0.f};
    for (int kt = w; kt < 128; kt += 4) {
      const unsigned short* bp = k0p + (long)(kt * 16 + l15) * 64 + g * 8;
      f32x4 acc = {0.f, 0.f, 0.f, 0.f};
      acc = mfma16(a0, *(const bf16x8*)bp, acc);
      acc = mfma16(a1, *(const bf16x8*)(bp + 32), acc);
#pragma unroll
      for (int j = 0; j < 4; j++) st[j] += __expf(acc[j] * 0.125f);
    }
#pragma unroll
    for (int j = 0; j < 4; j++) {
      float v = st[j];
      v += __shfl_xor(v, 1, 16);
      v += __shfl_xor(v, 2, 16);
      v += __shfl_xor(v, 4, 16);
      v += __shfl_xor(v, 8, 16);
      if (l15 == 0) sred[tt][w][g * 4 + j] = v;
    }
  }
  __syncthreads();
  if (tid < 32) {
    const int t2 = tid >> 4, rr = tid & 15;
    float s = sred[t2][0][rr] + sred[t2][1][rr] + sred[t2][2][rr] + sred[t2][3][rr];
    g_normT[bh * NN + rb + t2 * 16 + rr] = 1.0f / s;
  }
}

// ---------------------------------------------------------------------------
// Kernel 4: wave-private slab writer. Block = (bh, 128-key slab), 8 waves,
// 1 block/CU. fkS/k0S staged once (block barrier), then each wave sweeps its
// own rgs (w, w+8, ...) with a PRIVATE obuf slice -- no barriers, only
// wave-local lgkmcnt. Stores flow continuously, desynchronized per wave.
// ---------------------------------------------------------------------------
__global__ __launch_bounds__(512, 1) void k_write(
    const unsigned short* __restrict__ q0w, const unsigned short* __restrict__ k0w,
    const unsigned short* __restrict__ fqw, const unsigned short* __restrict__ fkw,
    float* __restrict__ out)
{
  const int bh = blockIdx.x;          // 0..31
  const int slab = blockIdx.y;        // 0..15
  const int tid = threadIdx.x;
  const int w = tid >> 6, l = tid & 63;
  const int l15 = l & 15, g = l >> 4;

  __shared__ unsigned short fkS[128][132];  // 33.8KB; row stride 264B -> 2-way-free reads
  __shared__ unsigned short k0S[128][68];   // 17.4KB
  __shared__ float obuf[8][16][130];        // wave-private 16x128 (+pad), 66.6KB

  const unsigned short* fkp = fkw + ((long)bh * NN + slab * 128) * 128;
  const unsigned short* k0p = k0w + ((long)bh * NN + slab * 128) * 64;
  const unsigned short* fqb = fqw + (long)bh * NN * 128;
  const unsigned short* q0b = q0w + (long)bh * NN * 64;
  const float* npb = g_normP + bh * NN;
  const float* ntb = g_normT + bh * NN;
  const long ob_p = (long)bh * NN * NN + slab * 128;
  const long ob_t = ob_p + (long)NBH * NN * NN;

  // ---- stage slab operands once (512 threads) ----
#pragma unroll
  for (int i = 0; i < 4; i++) {
    int c = i * 512 + tid, r = c >> 4, cc = c & 15;
    *(bf16x8*)&fkS[r][cc * 8] = *(const bf16x8*)(fkp + (long)r * 128 + cc * 8);
  }
#pragma unroll
  for (int i = 0; i < 2; i++) {
    int c = i * 512 + tid, r = c >> 3, cc = c & 7;
    *(bf16x8*)&k0S[r][cc * 8] = *(const bf16x8*)(k0p + (long)r * 64 + cc * 8);
  }
  __syncthreads();

  float (* const obufW)[130] = obuf[w];

  // ---- A-frag register sets (depth-1 double buffer, wave-local) ----
  bf16x8 aqA[4], aqB[4], akA[2], akB[2];
  f32x4 ipA, ipB, itA, itB;

#define PF(I, AQ, AK, IP, IT) {                                                \
    if ((I) < 16) {                                                            \
      const int qr_ = (w + (I) * 8) * 16;                                      \
      _Pragma("unroll")                                                        \
      for (int kk = 0; kk < 4; kk++)                                           \
        AQ[kk] = *(const bf16x8*)(fqb + (long)(qr_ + l15) * 128 + kk * 32 + g * 8); \
      _Pragma("unroll")                                                        \
      for (int kk = 0; kk < 2; kk++)                                           \
        AK[kk] = *(const bf16x8*)(q0b + (long)(qr_ + l15) * 64 + kk * 32 + g * 8);  \
      IP = *(const f32x4*)(npb + qr_ + g * 4);                                 \
      IT = *(const f32x4*)(ntb + qr_ + g * 4);                                 \
    }                                                                          \
  }

  // pred plane: full 128 keys by this wave (8 tiles)
#define CPRED(AQ, IP) {                                                        \
    _Pragma("unroll")                                                          \
    for (int t = 0; t < 8; t++) {                                              \
      const int key = t * 16 + l15;                                            \
      f32x4 acc = {0.f, 0.f, 0.f, 0.f};                                        \
      _Pragma("unroll")                                                        \
      for (int kk = 0; kk < 4; kk++)                                           \
        acc = mfma16(AQ[kk], *(const bf16x8*)&fkS[key][kk * 32 + g * 8], acc); \
      _Pragma("unroll")                                                        \
      for (int j = 0; j < 4; j++)                                              \
        obufW[g * 4 + j][key] = acc[j] * IP[j];                                \
    }                                                                          \
  }

#define CTRUE(AK, IT) {                                                        \
    _Pragma("unroll")                                                          \
    for (int t = 0; t < 8; t++) {                                              \
      const int key = t * 16 + l15;                                            \
      f32x4 acc = {0.f, 0.f, 0.f, 0.f};                                        \
      acc = mfma16(AK[0], *(const bf16x8*)&k0S[key][g * 8], acc);              \
      acc = mfma16(AK[1], *(const bf16x8*)&k0S[key][32 + g * 8], acc);         \
      _Pragma("unroll")                                                        \
      for (int j = 0; j < 4; j++)                                              \
        obufW[g * 4 + j][key] = __expf(acc[j] * 0.125f) * IT[j];               \
    }                                                                          \
  }

  // store the wave's 16x128 plane: 8 instrs, each 2 rows x 512B
#define STOREW(PL, I) {                                                        \
    const long ob = ((PL) ? ob_t : ob_p) + (long)((w + (I) * 8) * 16) * NN;    \
    const int col = (l & 31) * 4, rh = l >> 5;                                 \
    _Pragma("unroll")                                                          \
    for (int r = 0; r < 8; r++) {                                              \
      const int row = 2 * r + rh;                                              \
      f32x4 v = *(const f32x4*)&obufW[row][col];                               \
      *(f32x4*)(out + ob + (long)row * NN + col) = v;                          \
    }                                                                          \
  }

#define BODY(I, AQ, AK, IP, IT, PAQ, PAK, PIP, PIT) {                          \
    PF((I) + 1, PAQ, PAK, PIP, PIT);                                           \
    CPRED(AQ, IP);                                                             \
    asm volatile("s_waitcnt lgkmcnt(0)" ::: "memory");                         \
    STOREW(0, I);                                                              \
    asm volatile("s_waitcnt lgkmcnt(0)" ::: "memory");                         \
    CTRUE(AK, IT);                                                             \
    asm volatile("s_waitcnt lgkmcnt(0)" ::: "memory");                         \
    STOREW(1, I);                                                              \
    asm volatile("s_waitcnt lgkmcnt(0)" ::: "memory");                         \
  }

  PF(0, aqA, akA, ipA, itA);

#pragma unroll 1
  for (int i2 = 0; i2 < 8; i2++) {
    BODY(2 * i2,     aqA, akA, ipA, itA, aqB, akB, ipB, itB);
    BODY(2 * i2 + 1, aqB, akB, ipB, itB, aqA, akA, ipA, itA);
  }

#undef PF
#undef CPRED
#undef CTRUE
#undef STOREW
#undef BODY
}

extern "C" void kernel_launch(void* const* d_in, const int* in_sizes, int n_in,
                              void* d_out, int out_size, void* d_ws, size_t ws_size,
                              hipStream_t stream) {
  const float* x   = (const float*)d_in[0];
  const float* Wq  = (const float*)d_in[1];
  const float* bq  = (const float*)d_in[2];
  const float* Wk  = (const float*)d_in[3];
  const float* bk  = (const float*)d_in[4];
  const float* Wmq = (const float*)d_in[5];
  const float* bmq = (const float*)d_in[6];
  const float* Wmk = (const float*)d_in[7];
  const float* bmk = (const float*)d_in[8];
  float* out = (float*)d_out;

  // ws layout (bf16): q0[32][2048][64], k0[...], fq[32][2048][128], fk[...] = 48 MB
  unsigned short* q0w = (unsigned short*)d_ws;
  unsigned short* k0w = q0w + (long)NBH * NN * 64;
  unsigned short* fqw = k0w + (long)NBH * NN * 64;
  unsigned short* fkw = fqw + (long)NBH * NN * 128;

  hipLaunchKernelGGL(k_proj, dim3(1024), dim3(256), 0, stream,
                     x, Wq, bq, Wk, bk, Wmq, bmq, Wmk, bmk, q0w, k0w, fqw, fkw);
  hipLaunchKernelGGL(k_colsum1, dim3(NBH, 8), dim3(256), 0, stream, fkw);
  hipLaunchKernelGGL(k_normP, dim3(NBH, 16), dim3(256), 0, stream, fqw);
  hipLaunchKernelGGL(k_normT, dim3(NBH, 64), dim3(256), 0, stream, q0w, k0w);
  hipLaunchKernelGGL(k_write, dim3(NBH, 16), dim3(512), 0, stream,
                     q0w, k0w, fqw, fkw, out);
}

// Round 19
// 367.482 us; speedup vs baseline: 1.4940x; 1.2313x over previous
//
#include <hip/hip_runtime.h>

// ---------------------------------------------------------------------------
// HedgeHog attention distillation map: pred = (fq.fk^T) rownorm, true = softmax(q0.k0^T/8)
// Output [2,2,16,2048,2048] fp32 = 1.07 GiB -> HBM-write-bound.
//
// v19 = v18 (wave-private barrier-free slab sweep, 452us) + ONE lever:
// store run length 512B -> 1KB. Slab widened to 256 keys; LDS = exactly
// 160KB: fkS 64KB + k0S 32KB XOR-swizzled unpadded (granule ^= row&15/&7
// replaces padding; same involution on stage-write and compute-read) +
// obuf 4x16x256 fp32 (64KB). 4 waves/block, 256 blocks = ONE round,
// each store instr = one full 1KB-contiguous output row-slab.
// ---------------------------------------------------------------------------

typedef __attribute__((ext_vector_type(8))) short  bf16x8;
typedef __attribute__((ext_vector_type(4))) float  f32x4;

#define NN 2048
#define NBH 32

__device__ float g_part[NBH * 8 * 128];   // fk colsum partials
__device__ float g_normP[NBH * NN];       // 1 / pred row sum
__device__ float g_normT[NBH * NN];       // 1 / true row sum

__device__ __forceinline__ float bf2f(unsigned short u) {
  union { unsigned int i; float f; } v; v.i = ((unsigned int)u) << 16; return v.f;
}
__device__ __forceinline__ unsigned short f2bf(float f) {
  union { float f; unsigned int i; } v; v.f = f;
  unsigned int x = v.i;
  return (unsigned short)((x + 0x7FFFu + ((x >> 16) & 1u)) >> 16);  // RNE
}
__device__ __forceinline__ bf16x8 cvt8(const float* __restrict__ p) {
  bf16x8 v;
#pragma unroll
  for (int i = 0; i < 8; i++) v[i] = (short)f2bf(p[i]);
  return v;
}
__device__ __forceinline__ f32x4 mfma16(bf16x8 a, bf16x8 b, f32x4 c) {
  return __builtin_amdgcn_mfma_f32_16x16x32_bf16(a, b, c, 0, 0, 0);
}

// ---------------------------------------------------------------------------
// Kernel 1: projections + hedgehog features. One wave owns 16 rows.
// ---------------------------------------------------------------------------
__device__ __forceinline__ void proj_chain(
    const bf16x8 ax[2],
    const float* __restrict__ W1, const float* __restrict__ b1,
    const float* __restrict__ W2, const float* __restrict__ b2,
    unsigned short* __restrict__ o1w, unsigned short* __restrict__ o2w,
    unsigned short (*Tq)[72], unsigned short (*Tf)[136],
    long r0, int l15, int g, int l)
{
#pragma unroll
  for (int nt = 0; nt < 4; nt++) {
    f32x4 acc = {0.f, 0.f, 0.f, 0.f};
    acc = mfma16(ax[0], cvt8(W1 + (nt * 16 + l15) * 64 + g * 8), acc);
    acc = mfma16(ax[1], cvt8(W1 + (nt * 16 + l15) * 64 + 32 + g * 8), acc);
    float bv = b1[nt * 16 + l15];
#pragma unroll
    for (int j = 0; j < 4; j++)
      Tq[g * 4 + j][nt * 16 + l15] = f2bf(acc[j] + bv);   // C layout: row=(l>>4)*4+j, col=l&15
  }
#pragma unroll
  for (int i = 0; i < 2; i++) {
    int c = i * 64 + l;
    int r = c >> 3, cc = c & 7;
    *(bf16x8*)(o1w + (r0 + r) * 64 + cc * 8) = *(const bf16x8*)&Tq[r][cc * 8];
  }
  bf16x8 a1[2];
#pragma unroll
  for (int kk = 0; kk < 2; kk++)
    a1[kk] = *(const bf16x8*)&Tq[l15][kk * 32 + g * 8];
#pragma unroll
  for (int nt = 0; nt < 4; nt++) {
    f32x4 acc = {0.f, 0.f, 0.f, 0.f};
    acc = mfma16(a1[0], cvt8(W2 + (nt * 16 + l15) * 64 + g * 8), acc);
    acc = mfma16(a1[1], cvt8(W2 + (nt * 16 + l15) * 64 + 32 + g * 8), acc);
    float bv = b2[nt * 16 + l15];
#pragma unroll
    for (int j = 0; j < 4; j++) {
      float h = acc[j] + bv;
      Tf[g * 4 + j][nt * 16 + l15]      = f2bf(__expf(h));
      Tf[g * 4 + j][64 + nt * 16 + l15] = f2bf(__expf(-h));
    }
  }
#pragma unroll
  for (int i = 0; i < 4; i++) {
    int c = i * 64 + l;
    int r = c >> 4, cc = c & 15;
    *(bf16x8*)(o2w + (r0 + r) * 128 + cc * 8) = *(const bf16x8*)&Tf[r][cc * 8];
  }
}

__global__ __launch_bounds__(256) void k_proj(
    const float* __restrict__ x,
    const float* __restrict__ Wq,  const float* __restrict__ bq,
    const float* __restrict__ Wk,  const float* __restrict__ bk,
    const float* __restrict__ Wmq, const float* __restrict__ bmq,
    const float* __restrict__ Wmk, const float* __restrict__ bmk,
    unsigned short* __restrict__ q0w, unsigned short* __restrict__ k0w,
    unsigned short* __restrict__ fqw, unsigned short* __restrict__ fkw)
{
  const int tid = threadIdx.x;
  const int w = tid >> 6, l = tid & 63;
  const int l15 = l & 15, g = l >> 4;
  const long r0 = ((long)blockIdx.x * 4 + w) * 16;

  __shared__ unsigned short TqS[4][16][72];
  __shared__ unsigned short TfS[4][16][136];

  bf16x8 ax[2];
#pragma unroll
  for (int kk = 0; kk < 2; kk++)
    ax[kk] = cvt8(x + (r0 + l15) * 64 + kk * 32 + g * 8);

  proj_chain(ax, Wq, bq, Wmq, bmq, q0w, fqw, TqS[w], TfS[w], r0, l15, g, l);
  proj_chain(ax, Wk, bk, Wmk, bmk, k0w, fkw, TqS[w], TfS[w], r0, l15, g, l);
}

// ---------------------------------------------------------------------------
// Kernel 2: fk column-sum partials (bh, part): rows part*256..+255.
// ---------------------------------------------------------------------------
__global__ __launch_bounds__(256) void k_colsum1(const unsigned short* __restrict__ fkw)
{
  const int bh = blockIdx.x, part = blockIdx.y;
  const int tid = threadIdx.x;
  const int cg = tid & 15, rg = tid >> 4;
  const unsigned short* fkp = fkw + ((long)bh * NN + part * 256 + rg * 16) * 128 + cg * 8;

  float a8[8] = {0.f, 0.f, 0.f, 0.f, 0.f, 0.f, 0.f, 0.f};
#pragma unroll
  for (int r = 0; r < 16; r++) {
    bf16x8 v = *(const bf16x8*)(fkp + (long)r * 128);
#pragma unroll
    for (int j = 0; j < 8; j++) a8[j] += bf2f((unsigned short)v[j]);
  }
  __shared__ float red[16][132];
#pragma unroll
  for (int j = 0; j < 8; j++) red[rg][cg * 8 + j] = a8[j];
  __syncthreads();
  if (tid < 128) {
    float s = 0.f;
#pragma unroll
    for (int r = 0; r < 16; r++) s += red[r][tid];
    g_part[(bh * 8 + part) * 128 + tid] = s;
  }
}

// ---------------------------------------------------------------------------
// Kernel 3a: pred normalizers (factorized dot with fk colsums).
// ---------------------------------------------------------------------------
__global__ __launch_bounds__(256) void k_normP(const unsigned short* __restrict__ fqw)
{
  const int bh = blockIdx.x, rg = blockIdx.y;   // (32, 16)
  const int tid = threadIdx.x;

  __shared__ float sfk[128];
  if (tid < 128) {
    float s = 0.f;
#pragma unroll
    for (int pt = 0; pt < 8; pt++) s += g_part[bh * 1024 + pt * 128 + tid];
    sfk[tid] = s;
  }
  __syncthreads();
  if (tid < 128) {
    const int row = rg * 128 + tid;
    const unsigned short* p = fqw + ((long)bh * NN + row) * 128;
    float d = 0.f;
#pragma unroll
    for (int i = 0; i < 16; i++) {
      bf16x8 v = *(const bf16x8*)(p + i * 8);
#pragma unroll
      for (int jj = 0; jj < 8; jj++) d += bf2f((unsigned short)v[jj]) * sfk[i * 8 + jj];
    }
    g_normP[bh * NN + row] = 1.0f / d;
  }
}

// ---------------------------------------------------------------------------
// Kernel 3b: true normalizers. Grid (32, 64): 32 rows/block.
// ---------------------------------------------------------------------------
__global__ __launch_bounds__(256) void k_normT(
    const unsigned short* __restrict__ q0w, const unsigned short* __restrict__ k0w)
{
  const int bh = blockIdx.x, rb = blockIdx.y * 32;
  const int tid = threadIdx.x;
  const int w = tid >> 6, l = tid & 63;
  const int l15 = l & 15, g = l >> 4;

  __shared__ float sred[2][4][16];
  const unsigned short* k0p = k0w + (long)bh * NN * 64;

#pragma unroll
  for (int tt = 0; tt < 2; tt++) {
    const unsigned short* qp = q0w + ((long)bh * NN + rb + tt * 16) * 64;
    bf16x8 a0 = *(const bf16x8*)(qp + l15 * 64 + g * 8);
    bf16x8 a1 = *(const bf16x8*)(qp + l15 * 64 + 32 + g * 8);
    float st[4] = {0.f, 0.f, 0.f, 0.f};
    for (int kt = w; kt < 128; kt += 4) {
      const unsigned short* bp = k0p + (long)(kt * 16 + l15) * 64 + g * 8;
      f32x4 acc = {0.f, 0.f, 0.f, 0.f};
      acc = mfma16(a0, *(const bf16x8*)bp, acc);
      acc = mfma16(a1, *(const bf16x8*)(bp + 32), acc);
#pragma unroll
      for (int j = 0; j < 4; j++) st[j] += __expf(acc[j] * 0.125f);
    }
#pragma unroll
    for (int j = 0; j < 4; j++) {
      float v = st[j];
      v += __shfl_xor(v, 1, 16);
      v += __shfl_xor(v, 2, 16);
      v += __shfl_xor(v, 4, 16);
      v += __shfl_xor(v, 8, 16);
      if (l15 == 0) sred[tt][w][g * 4 + j] = v;
    }
  }
  __syncthreads();
  if (tid < 32) {
    const int t2 = tid >> 4, rr = tid & 15;
    float s = sred[t2][0][rr] + sred[t2][1][rr] + sred[t2][2][rr] + sred[t2][3][rr];
    g_normT[bh * NN + rb + t2 * 16 + rr] = 1.0f / s;
  }
}

// ---------------------------------------------------------------------------
// Kernel 4: wide-slab wave-private writer. Block = (bh, 256-key slab),
// 4 waves, 1 block/CU, 256 blocks (one round). XOR-swizzled unpadded
// operand tiles; each wave sweeps rgs w, w+4, ... barrier-free; store instr
// = one full 1KB-contiguous row-slab.
// ---------------------------------------------------------------------------
__global__ __launch_bounds__(256, 1) void k_write(
    const unsigned short* __restrict__ q0w, const unsigned short* __restrict__ k0w,
    const unsigned short* __restrict__ fqw, const unsigned short* __restrict__ fkw,
    float* __restrict__ out)
{
  const int bh = blockIdx.x;          // 0..31
  const int slab = blockIdx.y;        // 0..7 (256-key slab)
  const int tid = threadIdx.x;
  const int w = tid >> 6, l = tid & 63;
  const int l15 = l & 15, g = l >> 4;

  // exactly 160 KB: 65536 + 32768 + 65536
  __shared__ unsigned short fkS[256 * 128];   // XOR-swz: granule ^= row&15
  __shared__ unsigned short k0S[256 * 64];    // XOR-swz: granule ^= row&7
  __shared__ float obuf[4][16][256];          // wave-private 16x256 plane

  const unsigned short* fkp = fkw + ((long)bh * NN + slab * 256) * 128;
  const unsigned short* k0p = k0w + ((long)bh * NN + slab * 256) * 64;
  const unsigned short* fqb = fqw + (long)bh * NN * 128;
  const unsigned short* q0b = q0w + (long)bh * NN * 64;
  const float* npb = g_normP + bh * NN;
  const float* ntb = g_normT + bh * NN;
  const long ob_p = (long)bh * NN * NN + slab * 256;
  const long ob_t = ob_p + (long)NBH * NN * NN;

  // ---- stage slab operands once, XOR-swizzled (256 threads) ----
#pragma unroll
  for (int i = 0; i < 16; i++) {
    int c = i * 256 + tid;            // granule id 0..4095
    int r = c >> 4, gr = c & 15;      // row, granule-in-row
    *(bf16x8*)&fkS[r * 128 + (gr ^ (r & 15)) * 8] =
        *(const bf16x8*)(fkp + (long)r * 128 + gr * 8);
  }
#pragma unroll
  for (int i = 0; i < 8; i++) {
    int c = i * 256 + tid;            // granule id 0..2047
    int r = c >> 3, gr = c & 7;
    *(bf16x8*)&k0S[r * 64 + (gr ^ (r & 7)) * 8] =
        *(const bf16x8*)(k0p + (long)r * 64 + gr * 8);
  }
  __syncthreads();

  float (* const obufW)[256] = obuf[w];

  // ---- A-frag register sets (depth-1 double buffer, wave-local) ----
  bf16x8 aqA[4], aqB[4], akA[2], akB[2];
  f32x4 ipA, ipB, itA, itB;

#define PF(I, AQ, AK, IP, IT) {                                                \
    if ((I) < 32) {                                                            \
      const int qr_ = (w + (I) * 4) * 16;                                      \
      _Pragma("unroll")                                                        \
      for (int kk = 0; kk < 4; kk++)                                           \
        AQ[kk] = *(const bf16x8*)(fqb + (long)(qr_ + l15) * 128 + kk * 32 + g * 8); \
      _Pragma("unroll")                                                        \
      for (int kk = 0; kk < 2; kk++)                                           \
        AK[kk] = *(const bf16x8*)(q0b + (long)(qr_ + l15) * 64 + kk * 32 + g * 8);  \
      IP = *(const f32x4*)(npb + qr_ + g * 4);                                 \
      IT = *(const f32x4*)(ntb + qr_ + g * 4);                                 \
    }                                                                          \
  }

  // pred: 16 key-tiles; fkS granule (kk*4+g) ^ l15 of row key
#define CPRED(AQ, IP) {                                                        \
    _Pragma("unroll")                                                          \
    for (int t = 0; t < 16; t++) {                                             \
      const int key = t * 16 + l15;                                            \
      f32x4 acc = {0.f, 0.f, 0.f, 0.f};                                        \
      _Pragma("unroll")                                                        \
      for (int kk = 0; kk < 4; kk++)                                           \
        acc = mfma16(AQ[kk],                                                   \
              *(const bf16x8*)&fkS[key * 128 + ((kk * 4 + g) ^ l15) * 8], acc);\
      _Pragma("unroll")                                                        \
      for (int j = 0; j < 4; j++)                                              \
        obufW[g * 4 + j][key] = acc[j] * IP[j];                                \
    }                                                                          \
  }

#define CTRUE(AK, IT) {                                                        \
    _Pragma("unroll")                                                          \
    for (int t = 0; t < 16; t++) {                                             \
      const int key = t * 16 + l15;                                            \
      f32x4 acc = {0.f, 0.f, 0.f, 0.f};                                        \
      _Pragma("unroll")                                                        \
      for (int kk = 0; kk < 2; kk++)                                           \
        acc = mfma16(AK[kk],                                                   \
              *(const bf16x8*)&k0S[key * 64 + ((kk * 4 + g) ^ (l15 & 7)) * 8], acc); \
      _Pragma("unroll")                                                        \
      for (int j = 0; j < 4; j++)                                              \
        obufW[g * 4 + j][key] = __expf(acc[j] * 0.125f) * IT[j];               \
    }                                                                          \
  }

  // store the wave's 16x256 plane: 16 instrs, each one 1KB-contiguous row
#define STOREW(PL, I) {                                                        \
    const long ob = ((PL) ? ob_t : ob_p) + (long)((w + (I) * 4) * 16) * NN;    \
    _Pragma("unroll")                                                          \
    for (int r = 0; r < 16; r++) {                                             \
      f32x4 v = *(const f32x4*)&obufW[r][l * 4];                               \
      *(f32x4*)(out + ob + (long)r * NN + l * 4) = v;                          \
    }                                                                          \
  }

#define BODY(I, AQ, AK, IP, IT, PAQ, PAK, PIP, PIT) {                          \
    PF((I) + 1, PAQ, PAK, PIP, PIT);                                           \
    CPRED(AQ, IP);                                                             \
    asm volatile("s_waitcnt lgkmcnt(0)" ::: "memory");                         \
    STOREW(0, I);                                                              \
    asm volatile("s_waitcnt lgkmcnt(0)" ::: "memory");                         \
    CTRUE(AK, IT);                                                             \
    asm volatile("s_waitcnt lgkmcnt(0)" ::: "memory");                         \
    STOREW(1, I);                                                              \
    asm volatile("s_waitcnt lgkmcnt(0)" ::: "memory");                         \
  }

  PF(0, aqA, akA, ipA, itA);

#pragma unroll 1
  for (int i2 = 0; i2 < 16; i2++) {
    BODY(2 * i2,     aqA, akA, ipA, itA, aqB, akB, ipB, itB);
    BODY(2 * i2 + 1, aqB, akB, ipB, itB, aqA, akA, ipA, itA);
  }

#undef PF
#undef CPRED
#undef CTRUE
#undef STOREW
#undef BODY
}

extern "C" void kernel_launch(void* const* d_in, const int* in_sizes, int n_in,
                              void* d_out, int out_size, void* d_ws, size_t ws_size,
                              hipStream_t stream) {
  const float* x   = (const float*)d_in[0];
  const float* Wq  = (const float*)d_in[1];
  const float* bq  = (const float*)d_in[2];
  const float* Wk  = (const float*)d_in[3];
  const float* bk  = (const float*)d_in[4];
  const float* Wmq = (const float*)d_in[5];
  const float* bmq = (const float*)d_in[6];
  const float* Wmk = (const float*)d_in[7];
  const float* bmk = (const float*)d_in[8];
  float* out = (float*)d_out;

  // ws layout (bf16): q0[32][2048][64], k0[...], fq[32][2048][128], fk[...] = 48 MB
  unsigned short* q0w = (unsigned short*)d_ws;
  unsigned short* k0w = q0w + (long)NBH * NN * 64;
  unsigned short* fqw = k0w + (long)NBH * NN * 64;
  unsigned short* fkw = fqw + (long)NBH * NN * 128;

  hipLaunchKernelGGL(k_proj, dim3(1024), dim3(256), 0, stream,
                     x, Wq, bq, Wk, bk, Wmq, bmq, Wmk, bmk, q0w, k0w, fqw, fkw);
  hipLaunchKernelGGL(k_colsum1, dim3(NBH, 8), dim3(256), 0, stream, fkw);
  hipLaunchKernelGGL(k_normP, dim3(NBH, 16), dim3(256), 0, stream, fqw);
  hipLaunchKernelGGL(k_normT, dim3(NBH, 64), dim3(256), 0, stream, q0w, k0w);
  hipLaunchKernelGGL(k_write, dim3(NBH, 8), dim3(256), 0, stream,
                     q0w, k0w, fqw, fkw, out);
}